// Round 9
// baseline (217.159 us; speedup 1.0000x reference)
//
#include <hip/hip_runtime.h>

#define N_NODES 40000
#define N_EDGES 640000
#define HD 128
#define N_REL2 474
#define BN_EPS 1e-5f
#define NB_SCAN ((N_NODES + 255) / 256)  // 157 scan blocks

// K1: histogram of edge destinations
__global__ __launch_bounds__(256) void k_hist(
        const int* __restrict__ dst, int* __restrict__ counts) {
    int e = blockIdx.x * 256 + threadIdx.x;
    if (e < N_EDGES) atomicAdd(counts + dst[e], 1);
}

// K2a: per-block sum of 256 counts
__global__ __launch_bounds__(256) void k_scan_part(
        const int* __restrict__ counts, int* __restrict__ bsum) {
    __shared__ int ls[256];
    int t = threadIdx.x;
    int idx = blockIdx.x * 256 + t;
    ls[t] = (idx < N_NODES) ? counts[idx] : 0;
    __syncthreads();
    #pragma unroll
    for (int off = 128; off > 0; off >>= 1) {
        if (t < off) ls[t] += ls[t + off];
        __syncthreads();
    }
    if (t == 0) bsum[blockIdx.x] = ls[0];
}

// K2b: per-block local scan; block offset from replicated top-level scan of bsum
__global__ __launch_bounds__(256) void k_scan_down(
        const int* __restrict__ counts, const int* __restrict__ bsum,
        int* __restrict__ row_off, int* __restrict__ cursor) {
    __shared__ int btop[256];
    __shared__ int ls[256];
    int t = threadIdx.x;
    btop[t] = (t < NB_SCAN) ? bsum[t] : 0;
    __syncthreads();
    #pragma unroll
    for (int off = 1; off < 256; off <<= 1) {
        int tmp = (t >= off) ? btop[t - off] : 0;
        __syncthreads();
        btop[t] += tmp;
        __syncthreads();
    }
    int blockoff = (blockIdx.x == 0) ? 0 : btop[blockIdx.x - 1];
    int idx = blockIdx.x * 256 + t;
    int v = (idx < N_NODES) ? counts[idx] : 0;
    ls[t] = v;
    __syncthreads();
    #pragma unroll
    for (int off = 1; off < 256; off <<= 1) {
        int tmp = (t >= off) ? ls[t - off] : 0;
        __syncthreads();
        ls[t] += tmp;
        __syncthreads();
    }
    int excl = ls[t] - v + blockoff;
    if (idx < N_NODES) {
        row_off[idx] = excl;
        cursor[idx] = excl;
    }
    if (idx == N_NODES) row_off[N_NODES] = N_EDGES;
}

// K3: scatter packed (rel, dst) into CSR order — one 8B store per edge
__global__ __launch_bounds__(256) void k_sortrel(
        const int* __restrict__ dst, const int* __restrict__ rel_id,
        int* __restrict__ cursor, int2* __restrict__ sorted_rn) {
    int e = blockIdx.x * 256 + threadIdx.x;
    if (e < N_EDGES) {
        int d = dst[e];
        int p = atomicAdd(cursor + d, 1);
        sorted_rn[p] = make_int2(rel_id[e], d);
    }
}

// K4: RW = rel_emb @ neigh_w  (474 x 128 @ 128 x 128)
__global__ __launch_bounds__(128) void k_rw(
        const float* __restrict__ R, const float* __restrict__ W,
        float* __restrict__ RW) {
    __shared__ float row[HD];
    int r = blockIdx.x, c = threadIdx.x;
    row[c] = R[(size_t)r * HD + c];
    __syncthreads();
    float acc = 0.f;
    #pragma unroll 8
    for (int k = 0; k < HD; ++k) acc += row[k] * W[(size_t)k * HD + c];
    RW[(size_t)r * HD + c] = acc;
}

// K5: CSR-ordered dot+exp, 4 lanes per edge (64 edges / 256-block).
//     Consecutive edges share the ent row (L1-hit); R is L2-resident.
//     Quad reduce = 2 DPP shuffles. Writes (p, r) to its own CSR slot.
__global__ __launch_bounds__(256) void k_edge_dot(
        const float* __restrict__ ent_emb, const float* __restrict__ R,
        const int2* __restrict__ sorted_rn, float2* __restrict__ sorted_pr) {
    int t = threadIdx.x;
    int e = blockIdx.x * 64 + (t >> 2);
    if (e >= N_EDGES) return;
    int sub = t & 3;
    int2 rn = sorted_rn[e];  // same addr across quad -> broadcast
    const float4* rr = (const float4*)(R + (size_t)rn.x * HD);
    const float4* ee = (const float4*)(ent_emb + (size_t)rn.y * HD);
    float d = 0.f;
    #pragma unroll
    for (int k = 0; k < 8; ++k) {
        float4 a = rr[sub * 8 + k];
        float4 b = ee[sub * 8 + k];
        d += a.x * b.x + a.y * b.y + a.z * b.z + a.w * b.w;
    }
    d += __shfl_xor(d, 1, 64);
    d += __shfl_xor(d, 2, 64);
    // no max subtraction: |dot| < ~60 << 88 (f32 exp overflow)
    if (sub == 0) sorted_pr[e] = make_float2(__expf(d), __int_as_float(rn.x));
}

// K6: pure gather-accumulate. One wave per node.
//   lane = (g, c4): g in 0..3 takes edges j%4==g; c4 in 0..15 owns cols [c4*8, c4*8+8)
__global__ __launch_bounds__(256) void k_node_acc(
        const float* __restrict__ RW, const int* __restrict__ row_off,
        const float2* __restrict__ sorted_pr, float* __restrict__ h) {
    __shared__ __align__(8) float2 pr_s[4][64];
    int wave = threadIdx.x >> 6, lane = threadIdx.x & 63;
    int n = blockIdx.x * 4 + wave;
    if (n >= N_NODES) return;
    int beg = row_off[n], end = row_off[n + 1];
    int c4 = lane & 15, g = lane >> 4;
    float acc[8] = {};
    float lp = 0.f;
    const float4* RW4 = (const float4*)RW;
    for (int base = beg; base < end; base += 64) {
        int cnt = min(64, end - base);
        if (lane < cnt) pr_s[wave][lane] = sorted_pr[base + lane];
        // wave-synchronous LDS (in-order within wave; compiler inserts lgkmcnt)
        for (int j0 = 0; j0 < cnt; j0 += 4) {
            int eidx = j0 + g;
            if (eidx < cnt) {
                float2 v = pr_s[wave][eidx];
                float p = v.x;
                int r = __float_as_int(v.y);
                const float4* rowp = RW4 + (size_t)r * 32 + c4 * 2;
                float4 w0 = rowp[0], w1 = rowp[1];
                lp += p;
                acc[0] += p * w0.x; acc[1] += p * w0.y;
                acc[2] += p * w0.z; acc[3] += p * w0.w;
                acc[4] += p * w1.x; acc[5] += p * w1.y;
                acc[6] += p * w1.z; acc[7] += p * w1.w;
            }
        }
    }
    #pragma unroll
    for (int m = 16; m <= 32; m <<= 1) {
        lp += __shfl_xor(lp, m, 64);
        #pragma unroll
        for (int k = 0; k < 8; ++k) acc[k] += __shfl_xor(acc[k], m, 64);
    }
    float invl = (lp > 0.f) ? 1.f / lp : 0.f;
    if (g == 0) {
        float4* op = (float4*)(h + (size_t)n * HD + c4 * 8);
        op[0] = make_float4(acc[0] * invl, acc[1] * invl, acc[2] * invl, acc[3] * invl);
        op[1] = make_float4(acc[4] * invl, acc[5] * invl, acc[6] * invl, acc[7] * invl);
    }
}

// K7: per-column sum / sumsq over rows (block-partial -> global atomics)
__global__ __launch_bounds__(256) void k_stats(
        const float* __restrict__ Hout, float* __restrict__ colsum,
        float* __restrict__ colsumsq) {
    __shared__ float ls[256], lq[256];
    int t = threadIdx.x;
    int c = t & 127, half = t >> 7;
    int rbase = blockIdx.x * 64;
    float sum = 0.f, sq = 0.f;
    #pragma unroll 4
    for (int i = 0; i < 32; ++i) {
        int r = rbase + half + i * 2;
        float v = Hout[(size_t)r * HD + c];
        sum += v;
        sq += v * v;
    }
    ls[t] = sum;
    lq[t] = sq;
    __syncthreads();
    if (t < 128) {
        sum = ls[t] + ls[t + 128];
        sq = lq[t] + lq[t + 128];
        atomicAdd(colsum + c, sum);
        atomicAdd(colsumsq + c, sq);
    }
}

// K8: out = tanh((h - mean) * rstd * gamma + beta), in place; fast tanh via __expf
__global__ __launch_bounds__(256) void k_apply(
        float* __restrict__ Hout, const float* __restrict__ colsum,
        const float* __restrict__ colsumsq, const float* __restrict__ gamma,
        const float* __restrict__ beta) {
    int idx = blockIdx.x * 256 + threadIdx.x;  // float4 index
    if (idx >= N_NODES * HD / 4) return;
    int c0 = (idx * 4) & 127;
    float4 hv4 = ((const float4*)Hout)[idx];
    const float inv = 1.f / (float)N_NODES;
    float hv[4] = {hv4.x, hv4.y, hv4.z, hv4.w};
    float o[4];
    #pragma unroll
    for (int j = 0; j < 4; ++j) {
        int c = c0 + j;
        float mean = colsum[c] * inv;
        float var = colsumsq[c] * inv - mean * mean;
        float rstd = rsqrtf(var + BN_EPS);
        float x = (hv[j] - mean) * rstd * gamma[c] + beta[c];
        o[j] = 1.f - 2.f / (__expf(2.f * x) + 1.f);
    }
    ((float4*)Hout)[idx] = make_float4(o[0], o[1], o[2], o[3]);
}

extern "C" void kernel_launch(void* const* d_in, const int* in_sizes, int n_in,
                              void* d_out, int out_size, void* d_ws, size_t ws_size,
                              hipStream_t stream) {
    const float* ent_emb  = (const float*)d_in[0];
    const float* rel_emb  = (const float*)d_in[1];
    const float* neigh_w  = (const float*)d_in[2];
    const float* bn_gamma = (const float*)d_in[3];
    const float* bn_beta  = (const float*)d_in[4];
    const int*   rel_id   = (const int*)d_in[5];
    const int*   dst      = (const int*)d_in[6];
    float* out = (float*)d_out;

    // workspace layout (4-byte units) — first 40256 words are memset to 0
    int*      counts     = (int*)d_ws;                        // [40000]
    float*    colsum     = (float*)d_ws + 40000;              // [128]
    float*    colsumsq   = (float*)d_ws + 40128;              // [128]
    int*      row_off    = (int*)d_ws + 40256;                // [40001]
    int*      cursor     = (int*)d_ws + 80257;                // [40000]
    int2*     sorted_rn  = (int2*)((float*)d_ws + 120258);    // [640000] 8B-aligned
    float2*   sorted_pr  = (float2*)((float*)d_ws + 1400258); // [640000] 8B-aligned
    float*    RW         = (float*)d_ws + 2680258;            // [474*128]
    int*      bsum       = (int*)d_ws + 2680258 + N_REL2 * HD;  // [NB_SCAN]

    hipMemsetAsync(d_ws, 0, (size_t)40256 * 4, stream);

    k_hist<<<(N_EDGES + 255) / 256, 256, 0, stream>>>(dst, counts);
    k_scan_part<<<NB_SCAN, 256, 0, stream>>>(counts, bsum);
    k_scan_down<<<NB_SCAN, 256, 0, stream>>>(counts, bsum, row_off, cursor);
    k_sortrel<<<(N_EDGES + 255) / 256, 256, 0, stream>>>(dst, rel_id, cursor, sorted_rn);
    k_rw<<<N_REL2, 128, 0, stream>>>(rel_emb, neigh_w, RW);
    k_edge_dot<<<N_EDGES / 64, 256, 0, stream>>>(ent_emb, rel_emb, sorted_rn, sorted_pr);
    k_node_acc<<<N_NODES / 4, 256, 0, stream>>>(RW, row_off, sorted_pr, out);
    k_stats<<<N_NODES / 64, 256, 0, stream>>>(out, colsum, colsumsq);
    k_apply<<<N_NODES * HD / 4 / 256, 256, 0, stream>>>(out, colsum, colsumsq, bn_gamma, bn_beta);
}

// Round 10
// 175.170 us; speedup vs baseline: 1.2397x; 1.2397x over previous
//
#include <hip/hip_runtime.h>
#include <hip/hip_fp16.h>

#define N_NODES 40000
#define N_EDGES 640000
#define HD 128
#define N_REL2 474
#define BN_EPS 1e-5f
#define NB_SCAN ((N_NODES + 255) / 256)  // 157 scan blocks

// K1: histogram of edge destinations
__global__ __launch_bounds__(256) void k_hist(
        const int* __restrict__ dst, int* __restrict__ counts) {
    int e = blockIdx.x * 256 + threadIdx.x;
    if (e < N_EDGES) atomicAdd(counts + dst[e], 1);
}

// K2a: per-block sum of 256 counts
__global__ __launch_bounds__(256) void k_scan_part(
        const int* __restrict__ counts, int* __restrict__ bsum) {
    __shared__ int ls[256];
    int t = threadIdx.x;
    int idx = blockIdx.x * 256 + t;
    ls[t] = (idx < N_NODES) ? counts[idx] : 0;
    __syncthreads();
    #pragma unroll
    for (int off = 128; off > 0; off >>= 1) {
        if (t < off) ls[t] += ls[t + off];
        __syncthreads();
    }
    if (t == 0) bsum[blockIdx.x] = ls[0];
}

// K2b: per-block local scan; block offset from replicated top-level scan of bsum
__global__ __launch_bounds__(256) void k_scan_down(
        const int* __restrict__ counts, const int* __restrict__ bsum,
        int* __restrict__ row_off, int* __restrict__ cursor) {
    __shared__ int btop[256];
    __shared__ int ls[256];
    int t = threadIdx.x;
    btop[t] = (t < NB_SCAN) ? bsum[t] : 0;
    __syncthreads();
    #pragma unroll
    for (int off = 1; off < 256; off <<= 1) {
        int tmp = (t >= off) ? btop[t - off] : 0;
        __syncthreads();
        btop[t] += tmp;
        __syncthreads();
    }
    int blockoff = (blockIdx.x == 0) ? 0 : btop[blockIdx.x - 1];
    int idx = blockIdx.x * 256 + t;
    int v = (idx < N_NODES) ? counts[idx] : 0;
    ls[t] = v;
    __syncthreads();
    #pragma unroll
    for (int off = 1; off < 256; off <<= 1) {
        int tmp = (t >= off) ? ls[t - off] : 0;
        __syncthreads();
        ls[t] += tmp;
        __syncthreads();
    }
    int excl = ls[t] - v + blockoff;
    if (idx < N_NODES) {
        row_off[idx] = excl;
        cursor[idx] = excl;
    }
    if (idx == N_NODES) row_off[N_NODES] = N_EDGES;
}

// K3: scatter packed (rel, dst) into CSR order — one 8B store per edge
__global__ __launch_bounds__(256) void k_sortrel(
        const int* __restrict__ dst, const int* __restrict__ rel_id,
        int* __restrict__ cursor, int2* __restrict__ sorted_rn) {
    int e = blockIdx.x * 256 + threadIdx.x;
    if (e < N_EDGES) {
        int d = dst[e];
        int p = atomicAdd(cursor + d, 1);
        sorted_rn[p] = make_int2(rel_id[e], d);
    }
}

// K4: ent_emb -> fp16 (8 floats per thread)
__global__ __launch_bounds__(256) void k_ent_h(
        const float* __restrict__ ent, __half* __restrict__ ent_h) {
    int i = blockIdx.x * 256 + threadIdx.x;  // group of 8 floats
    if (i >= N_NODES * HD / 8) return;
    float4 a = ((const float4*)ent)[i * 2];
    float4 b = ((const float4*)ent)[i * 2 + 1];
    __half2* o = (__half2*)(ent_h + (size_t)i * 8);
    o[0] = __floats2half2_rn(a.x, a.y);
    o[1] = __floats2half2_rn(a.z, a.w);
    o[2] = __floats2half2_rn(b.x, b.y);
    o[3] = __floats2half2_rn(b.z, b.w);
}

// K5: RW = rel_emb @ neigh_w (f32 math) -> fp16; also emit R_h = fp16(rel_emb)
__global__ __launch_bounds__(128) void k_rw(
        const float* __restrict__ R, const float* __restrict__ W,
        __half* __restrict__ RW_h, __half* __restrict__ R_h) {
    __shared__ float row[HD];
    int r = blockIdx.x, c = threadIdx.x;
    float rv = R[(size_t)r * HD + c];
    row[c] = rv;
    R_h[(size_t)r * HD + c] = __float2half(rv);
    __syncthreads();
    float acc = 0.f;
    #pragma unroll 8
    for (int k = 0; k < HD; ++k) acc += row[k] * W[(size_t)k * HD + c];
    RW_h[(size_t)r * HD + c] = __float2half(acc);
}

// K6: CSR-ordered dot+exp, 16 lanes/edge, fp16 rows (1 x 16B load per operand).
//     Consecutive edges share the ent row (L1-hit); R_h (121 KB) is L2-resident.
__global__ __launch_bounds__(256) void k_edge_dot(
        const __half* __restrict__ ent_h, const __half* __restrict__ R_h,
        const int2* __restrict__ sorted_rn, float2* __restrict__ sorted_pr) {
    int t = threadIdx.x;
    int e = blockIdx.x * 16 + (t >> 4);
    int lam = t & 15;
    int2 rn = sorted_rn[e];  // broadcast within 16-lane group
    float4 av = ((const float4*)(R_h + (size_t)rn.x * HD))[lam];
    float4 bv = ((const float4*)(ent_h + (size_t)rn.y * HD))[lam];
    const __half2* ah = (const __half2*)&av;
    const __half2* bh = (const __half2*)&bv;
    float d = 0.f;
    #pragma unroll
    for (int k = 0; k < 4; ++k) {
        float2 af = __half22float2(ah[k]);
        float2 bf = __half22float2(bh[k]);
        d += af.x * bf.x + af.y * bf.y;
    }
    #pragma unroll
    for (int m = 8; m >= 1; m >>= 1) d += __shfl_xor(d, m, 64);  // within 16-group
    // no max subtraction: |dot| < ~60 << 88 (f32 exp overflow)
    if (lam == 0) sorted_pr[e] = make_float2(__expf(d), __int_as_float(rn.x));
}

// K7: pure gather-accumulate, fp16 RW rows. One wave per node.
//   lane = (g, c4): g in 0..3 takes edges j%4==g; c4 owns cols [c4*8, c4*8+8)
//   one 16B load (8 halfs) per edge per lane.
__global__ __launch_bounds__(256) void k_node_acc(
        const __half* __restrict__ RW_h, const int* __restrict__ row_off,
        const float2* __restrict__ sorted_pr, float* __restrict__ h) {
    __shared__ __align__(8) float2 pr_s[4][64];
    int wave = threadIdx.x >> 6, lane = threadIdx.x & 63;
    int n = blockIdx.x * 4 + wave;
    if (n >= N_NODES) return;
    int beg = row_off[n], end = row_off[n + 1];
    int c4 = lane & 15, g = lane >> 4;
    float acc[8] = {};
    float lp = 0.f;
    for (int base = beg; base < end; base += 64) {
        int cnt = min(64, end - base);
        if (lane < cnt) pr_s[wave][lane] = sorted_pr[base + lane];
        // wave-synchronous LDS (in-order within wave; compiler inserts lgkmcnt)
        for (int j0 = 0; j0 < cnt; j0 += 4) {
            int eidx = j0 + g;
            if (eidx < cnt) {
                float2 v = pr_s[wave][eidx];
                float p = v.x;
                int r = __float_as_int(v.y);
                float4 wv = ((const float4*)(RW_h + (size_t)r * HD))[c4];
                const __half2* wh = (const __half2*)&wv;
                lp += p;
                #pragma unroll
                for (int k = 0; k < 4; ++k) {
                    float2 wf = __half22float2(wh[k]);
                    acc[2 * k]     += p * wf.x;
                    acc[2 * k + 1] += p * wf.y;
                }
            }
        }
    }
    #pragma unroll
    for (int m = 16; m <= 32; m <<= 1) {
        lp += __shfl_xor(lp, m, 64);
        #pragma unroll
        for (int k = 0; k < 8; ++k) acc[k] += __shfl_xor(acc[k], m, 64);
    }
    float invl = (lp > 0.f) ? 1.f / lp : 0.f;
    if (g == 0) {
        float4* op = (float4*)(h + (size_t)n * HD + c4 * 8);
        op[0] = make_float4(acc[0] * invl, acc[1] * invl, acc[2] * invl, acc[3] * invl);
        op[1] = make_float4(acc[4] * invl, acc[5] * invl, acc[6] * invl, acc[7] * invl);
    }
}

// K8: per-column sum / sumsq over rows (block-partial -> global atomics)
__global__ __launch_bounds__(256) void k_stats(
        const float* __restrict__ Hout, float* __restrict__ colsum,
        float* __restrict__ colsumsq) {
    __shared__ float ls[256], lq[256];
    int t = threadIdx.x;
    int c = t & 127, half = t >> 7;
    int rbase = blockIdx.x * 64;
    float sum = 0.f, sq = 0.f;
    #pragma unroll 4
    for (int i = 0; i < 32; ++i) {
        int r = rbase + half + i * 2;
        float v = Hout[(size_t)r * HD + c];
        sum += v;
        sq += v * v;
    }
    ls[t] = sum;
    lq[t] = sq;
    __syncthreads();
    if (t < 128) {
        sum = ls[t] + ls[t + 128];
        sq = lq[t] + lq[t + 128];
        atomicAdd(colsum + c, sum);
        atomicAdd(colsumsq + c, sq);
    }
}

// K9: out = tanh((h - mean) * rstd * gamma + beta), in place; fast tanh via __expf
__global__ __launch_bounds__(256) void k_apply(
        float* __restrict__ Hout, const float* __restrict__ colsum,
        const float* __restrict__ colsumsq, const float* __restrict__ gamma,
        const float* __restrict__ beta) {
    int idx = blockIdx.x * 256 + threadIdx.x;  // float4 index
    if (idx >= N_NODES * HD / 4) return;
    int c0 = (idx * 4) & 127;
    float4 hv4 = ((const float4*)Hout)[idx];
    const float inv = 1.f / (float)N_NODES;
    float hv[4] = {hv4.x, hv4.y, hv4.z, hv4.w};
    float o[4];
    #pragma unroll
    for (int j = 0; j < 4; ++j) {
        int c = c0 + j;
        float mean = colsum[c] * inv;
        float var = colsumsq[c] * inv - mean * mean;
        float rstd = rsqrtf(var + BN_EPS);
        float x = (hv[j] - mean) * rstd * gamma[c] + beta[c];
        o[j] = 1.f - 2.f / (__expf(2.f * x) + 1.f);
    }
    ((float4*)Hout)[idx] = make_float4(o[0], o[1], o[2], o[3]);
}

extern "C" void kernel_launch(void* const* d_in, const int* in_sizes, int n_in,
                              void* d_out, int out_size, void* d_ws, size_t ws_size,
                              hipStream_t stream) {
    const float* ent_emb  = (const float*)d_in[0];
    const float* rel_emb  = (const float*)d_in[1];
    const float* neigh_w  = (const float*)d_in[2];
    const float* bn_gamma = (const float*)d_in[3];
    const float* bn_beta  = (const float*)d_in[4];
    const int*   rel_id   = (const int*)d_in[5];
    const int*   dst      = (const int*)d_in[6];
    float* out = (float*)d_out;

    // workspace layout (4-byte units) — first 40256 words are memset to 0
    int*      counts     = (int*)d_ws;                        // [40000]
    float*    colsum     = (float*)d_ws + 40000;              // [128]
    float*    colsumsq   = (float*)d_ws + 40128;              // [128]
    int*      row_off    = (int*)d_ws + 40256;                // [40001]
    int*      cursor     = (int*)d_ws + 80257;                // [40000]
    int2*     sorted_rn  = (int2*)((float*)d_ws + 120258);    // [640000] 8B-aligned
    float2*   sorted_pr  = (float2*)((float*)d_ws + 1400258); // [640000] 8B-aligned
    __half*   RW_h       = (__half*)((float*)d_ws + 2680260); // [474*128] 16B-aligned
    __half*   R_h        = (__half*)((float*)d_ws + 2710596); // [474*128]
    __half*   ent_h      = (__half*)((float*)d_ws + 2740932); // [40000*128]
    int*      bsum       = (int*)d_ws + 5300932;              // [NB_SCAN]

    hipMemsetAsync(d_ws, 0, (size_t)40256 * 4, stream);

    k_hist<<<(N_EDGES + 255) / 256, 256, 0, stream>>>(dst, counts);
    k_scan_part<<<NB_SCAN, 256, 0, stream>>>(counts, bsum);
    k_scan_down<<<NB_SCAN, 256, 0, stream>>>(counts, bsum, row_off, cursor);
    k_ent_h<<<(N_NODES * HD / 8 + 255) / 256, 256, 0, stream>>>(ent_emb, ent_h);
    k_sortrel<<<(N_EDGES + 255) / 256, 256, 0, stream>>>(dst, rel_id, cursor, sorted_rn);
    k_rw<<<N_REL2, 128, 0, stream>>>(rel_emb, neigh_w, RW_h, R_h);
    k_edge_dot<<<N_EDGES / 16, 256, 0, stream>>>(ent_h, R_h, sorted_rn, sorted_pr);
    k_node_acc<<<N_NODES / 4, 256, 0, stream>>>(RW_h, row_off, sorted_pr, out);
    k_stats<<<N_NODES / 64, 256, 0, stream>>>(out, colsum, colsumsq);
    k_apply<<<N_NODES * HD / 4 / 256, 256, 0, stream>>>(out, colsum, colsumsq, bn_gamma, bn_beta);
}